// Round 1
// baseline (59137.457 us; speedup 1.0000x reference)
//
#include <hip/hip_runtime.h>
#include <math.h>

// ---------------------------------------------------------------------------
// FastFFTNet autoregressive sampler on MI355X.
// Persistent multi-workgroup pipeline: weights register-resident per stage,
// spin-flag handoffs through device-coherent (agent-scope) atomics.
//
// Roles (33 blocks x 512 threads):
//   bid 0      : SL  — sampler + end_w matvec + fused layer-0 (table lookups)
//   bid 1..10  : A_j (j=bid)     — layer j: h rows 0..127,  W_o cols 0..127
//   bid 11..20 : B_j (j=bid-10)  — layer j: h rows 128..255, W_o cols 128..255
//   bid 21,22  : A_0/B_0         — layer 0: W_o col-halves applied to h_0
//   bid 23..32 : helper_j (j=bid-22) — WV_past[j] @ xin_j(t-d_j), runs ahead
// ---------------------------------------------------------------------------

#define T_STEPS 2048
#define NBLK    33

// ws float offsets
#define OFF_EMBT   0           // tanh(emb_raw)            [256][256]
#define OFF_WPET   65536       // WV_present[0] @ emb^T    [class][256]
#define OFF_WVPET  131072      // WV_past[0]    @ emb^T    [class][256]
#define OFF_RINGS  196608      // ring_j at +512*((1<<j)-1), size 512<<j floats
#define OFF_TAPS   1244672     // [10][16][256]
#define OFF_Z      1285632     // [11][2][256]
#define OFF_H0     1291264     // [256]
#define WS_FLOATS  1291520

// flag layout (ints, each flag padded to 32 ints = 128 B)
#define FZ(j,s)  ((((j)*2)+(s))*32)     // 0..21
#define FTAP(j)  ((21+(j))*32)          // j=1..10 -> 22..31
#define FH0      (32*32)
#define FBAR(b)  ((40+(b))*32)          // init barriers, NOT zeroed
#define NZERO_INTS  1280
#define NFLAG_INTS  4096

__device__ __forceinline__ float ldc(const float* p) {
  int v = __hip_atomic_load((const int*)p, __ATOMIC_RELAXED, __HIP_MEMORY_SCOPE_AGENT);
  return __int_as_float(v);
}
__device__ __forceinline__ void stc(float* p, float x) {
  __hip_atomic_store((int*)p, __float_as_int(x), __ATOMIC_RELAXED, __HIP_MEMORY_SCOPE_AGENT);
}
__device__ __forceinline__ void wait1(int* f, int want) {
  // relaxed spin + one acquire; safety valve so a bug can't hang the bench
  int it = 0;
  while (__hip_atomic_load(f, __ATOMIC_RELAXED, __HIP_MEMORY_SCOPE_AGENT) < want) {
    if (++it > (1 << 24)) break;
  }
  (void)__hip_atomic_load(f, __ATOMIC_ACQUIRE, __HIP_MEMORY_SCOPE_AGENT);
}
__device__ __forceinline__ void post(int* f, int v) {
  __hip_atomic_store(f, v, __ATOMIC_RELEASE, __HIP_MEMORY_SCOPE_AGENT);
}

__global__ __launch_bounds__(512)
void fftnet_kernel(const float* __restrict__ y, const float* __restrict__ samples,
                   const float* __restrict__ emb_raw, const float* __restrict__ condW,
                   const float* __restrict__ WV_past, const float* __restrict__ WV_present,
                   const float* __restrict__ W_o_w, const float* __restrict__ W_o_b,
                   const float* __restrict__ end_w, const float* __restrict__ end_b,
                   int* __restrict__ out, float* __restrict__ ws)
{
  const int tid = threadIdx.x;
  const int bid = blockIdx.x;
  int* iflags = (int*)(ws + WS_FLOATS);

  __shared__ float s_x[256];
  __shared__ float s_h[256];
  __shared__ float s_p[1024];
  __shared__ float s_cond[16 * 256];
  __shared__ float s_m[320];
  __shared__ unsigned long long s_mask[8];
  __shared__ int s_i[16];

  // ---- init phase A: block 0 zeroes the pipeline flags (ws is 0xAA-poisoned)
  if (bid == 0) {
    for (int i = tid; i < NZERO_INTS; i += 512)
      __hip_atomic_store(iflags + i, 0, __ATOMIC_RELAXED, __HIP_MEMORY_SCOPE_AGENT);
  }
  // ---- init phase B: embt = tanh(emb_raw), distributed (sc-coherent stores)
  for (int i = bid * 512 + tid; i < 65536; i += NBLK * 512)
    stc(ws + OFF_EMBT + i, tanhf(emb_raw[i]));

  // barrier round 1 (poison is negative -> monotone waits safe)
  __syncthreads();
  if (tid == 0) post(iflags + FBAR(bid), 1);
  if (tid < NBLK) wait1(iflags + FBAR(tid), 1);
  __syncthreads();

  // ---- init phase C: WPEt / WVP0Et tables (row per class), distributed
  for (int n = bid; n < 512; n += NBLK) {
    const float* wmat = (n < 256) ? WV_present : WV_past; // layer-0 slice of each
    int cls = n & 255;
    int c = tid & 255, s2 = tid >> 8;
    float acc = 0.f;
    for (int k = 128 * s2; k < 128 * s2 + 128; ++k)
      acc += wmat[c * 256 + k] * ws[OFF_EMBT + cls * 256 + k];
    s_p[s2 * 256 + c] = acc;
    __syncthreads();
    if (tid < 256)
      stc(ws + ((n < 256) ? OFF_WPET : OFF_WVPET) + cls * 256 + tid, s_p[tid] + s_p[256 + tid]);
    __syncthreads();
  }

  // barrier round 2
  __syncthreads();
  if (tid == 0) post(iflags + FBAR(bid), 2);
  if (tid < NBLK) wait1(iflags + FBAR(tid), 2);
  __syncthreads();

  // =========================================================================
  if (bid == 0) {
    // ------------------------- SL: sampler ---------------------------------
    const int c = tid & 255, s2 = tid >> 8;  // s2 in {0,1}
    float we[128];
#pragma unroll
    for (int i = 0; i < 128; ++i) we[i] = end_w[c * 256 + 128 * s2 + i];
    const float eb = end_b[c];
    const float b10 = W_o_b[10 * 256 + c];
    // cond layer 0, all 16 frames
    for (int e = tid; e < 4096; e += 512) {
      int f = e >> 8, r = e & 255;
      float a = 0.f;
      for (int q = 0; q < 80; ++q) a += condW[r * 80 + q] * y[q * 16 + f];
      s_cond[f * 256 + r] = a;
    }
    __syncthreads();
    float* h0 = ws + OFF_H0;
    float* ring0 = ws + OFF_RINGS;
    float* zA = ws + OFF_Z + (10 * 2 + 0) * 256;
    float* zB = ws + OFF_Z + (10 * 2 + 1) * 256;
    float* ring10 = ws + OFF_RINGS + 512 * 1023;
    // prologue: t=0 state. x0 = emb[127]; h_0(0) = relu(cond_0(0) + WPEt[127])
    if (tid < 256) {
      float hv = s_cond[tid] + ws[OFF_WPET + 127 * 256 + tid];
      stc(h0 + tid, fmaxf(hv, 0.f));
      stc(ring0 + tid, ws[OFF_EMBT + 127 * 256 + tid]);   // slot 0 = xin_0(0)
    }
    __syncthreads();
    if (tid == 0) post(iflags + FH0, 1);
    int pidx = 127;
    const int lane = tid & 63, w = tid >> 6;

    for (int t = 0; t < T_STEPS; ++t) {
      // prefetch next-step past-tap column (depends only on pidx)
      float qv = (tid < 256) ? ws[OFF_WVPET + pidx * 256 + tid] : 0.f;
      if (tid < 2) wait1(iflags + FZ(10, tid), t + 1);
      __syncthreads();
      if (tid < 256) {
        float xo = ldc(zA + tid) + ldc(zB + tid) + b10 + ldc(ring10 + (t & 2047) * 256 + tid);
        s_x[tid] = fmaxf(xo, 0.f);
      }
      __syncthreads();
      // logits = end_w @ x + end_b
      float acc = 0.f;
#pragma unroll
      for (int i = 0; i < 128; ++i) acc += we[i] * s_x[128 * s2 + i];
      s_p[s2 * 256 + c] = acc;
      __syncthreads();
      float logit = 0.f;
      if (tid < 256) logit = s_p[tid] + s_p[256 + tid] + eb;
      // wave-level max reduce (only waves 0..3 meaningful)
      float vmax = (tid < 256) ? logit : -3.4e38f;
#pragma unroll
      for (int d = 32; d > 0; d >>= 1) vmax = fmaxf(vmax, __shfl_xor(vmax, d, 64));
      if (lane == 0) s_m[280 + w] = vmax;
      __syncthreads();
      float mx = fmaxf(fmaxf(s_m[280], s_m[281]), fmaxf(s_m[282], s_m[283]));
      float e = (tid < 256) ? expf(logit - mx) : 0.f;
      float vs = e;
#pragma unroll
      for (int d = 32; d > 0; d >>= 1) vs += __shfl_xor(vs, d, 64);
      if (lane == 0) s_m[288 + w] = vs;
      __syncthreads();
      float ssum = s_m[288] + s_m[289] + s_m[290] + s_m[291];
      float u = samples[t];
      // inclusive prefix scan of p = e/ssum across 256
      float p = (tid < 256) ? (e / ssum) : 0.f;
      float v = p;
#pragma unroll
      for (int d = 1; d < 64; d <<= 1) {
        float o = __shfl_up(v, (unsigned)d, 64);
        if (lane >= d) v += o;
      }
      if (tid < 256 && lane == 63) s_m[256 + w] = v;
      __syncthreads();
      float offs = 0.f;
      if (tid < 256) for (int k = 0; k < w; ++k) offs += s_m[256 + k];
      float cum = v + offs;
      unsigned long long msk = __ballot(tid < 256 && (cum > u));
      if (lane == 0) s_mask[w] = msk;
      __syncthreads();
      if (tid == 0) {
        int idx = 0;
        for (int k = 0; k < 4; ++k) {
          unsigned long long m2 = s_mask[k];
          if (m2) { idx = k * 64 + (int)__builtin_ctzll(m2); break; }
        }
        s_i[0] = idx;
        out[t] = idx;
      }
      __syncthreads();
      int idx = s_i[0];
      if (t + 1 < T_STEPS) {
        int f1 = (t + 1) >> 7;
        if (tid < 256) {
          float hv = s_cond[f1 * 256 + tid] + ws[OFF_WPET + idx * 256 + tid] + qv;
          stc(h0 + tid, fmaxf(hv, 0.f));
          stc(ring0 + ((t + 1) & 1) * 256 + tid, ws[OFF_EMBT + idx * 256 + tid]);
        }
        __syncthreads();
        if (tid == 0) post(iflags + FH0, t + 2);
      }
      pidx = idx;
    }

  } else if (bid <= 22) {
    // ---------------- layer stages A/B -------------------------------------
    int j, side;
    if (bid <= 10)      { j = bid;      side = 0; }
    else if (bid <= 20) { j = bid - 10; side = 1; }
    else                { j = 0;        side = bid - 21; }
    const int base = side * 128;
    float wo[64];
    {
      const float* W = W_o_w + j * 65536;
      int c = tid & 255, s2 = tid >> 8;
#pragma unroll
      for (int i = 0; i < 64; ++i) wo[i] = W[c * 256 + base + 64 * s2 + i];
    }

    if (j == 0) {
      float* h0 = ws + OFF_H0;
      float* zout = ws + OFF_Z + side * 256;
      const int c = tid & 255, s2 = tid >> 8;
      for (int t = 0; t < T_STEPS; ++t) {
        if (tid == 0) wait1(iflags + FH0, t + 1);
        __syncthreads();
        if (tid < 128) s_h[tid] = ldc(h0 + base + tid);
        __syncthreads();
        float acc = 0.f;
#pragma unroll
        for (int i = 0; i < 64; ++i) acc += wo[i] * s_h[64 * s2 + i];
        s_p[s2 * 256 + c] = acc;
        __syncthreads();
        if (tid < 256) stc(zout + tid, s_p[tid] + s_p[256 + tid]);
        __syncthreads();
        if (tid == 0) post(iflags + FZ(0, side), t + 1);
      }
    } else {
      float wp[64];
      {
        const float* W = WV_present + j * 65536;
        int r = tid & 127, s = tid >> 7;
#pragma unroll
        for (int i = 0; i < 64; ++i) wp[i] = W[(base + r) * 256 + 64 * s + i];
      }
      const float bprev = W_o_b[(j - 1) * 256 + (tid & 255)];
      // conditioning rows [base, base+128) for all 16 frames
      for (int e = tid; e < 2048; e += 512) {
        int f = e >> 7, rr = e & 127;
        float a = 0.f;
        for (int q = 0; q < 80; ++q) a += condW[(j * 256 + base + rr) * 80 + q] * y[q * 16 + f];
        s_cond[f * 128 + rr] = a;
      }
      __syncthreads();
      const int dj = 1 << j, maskj = 2 * dj - 1;
      const int dprev = 1 << (j - 1), maskp = 2 * dprev - 1;
      float* ringp = ws + OFF_RINGS + 512 * (dprev - 1);
      float* ringj = ws + OFF_RINGS + 512 * (dj - 1);
      float* zpa = ws + OFF_Z + ((j - 1) * 2 + 0) * 256;
      float* zpb = ws + OFF_Z + ((j - 1) * 2 + 1) * 256;
      float* zout = ws + OFF_Z + (j * 2 + side) * 256;
      float* tapj = ws + OFF_TAPS + (j - 1) * 16 * 256;

      for (int t = 0; t < T_STEPS; ++t) {
        // tap is produced ahead of time -> wait+load it first, overlap z-wait
        if (tid == 0) wait1(iflags + FTAP(j), t + 1);
        __syncthreads();
        float tv = (tid < 128) ? ldc(tapj + (t & 15) * 256 + base + tid) : 0.f;
        if (tid < 2) wait1(iflags + FZ(j - 1, tid), t + 1);
        __syncthreads();
        if (tid < 256) {
          float xv = ldc(zpa + tid) + ldc(zpb + tid) + bprev
                   + ldc(ringp + (t & maskp) * 256 + tid);
          xv = fmaxf(xv, 0.f);
          s_x[tid] = xv;
          if (side == 0) stc(ringj + (t & maskj) * 256 + tid, xv);  // publish xin_j(t)
        }
        __syncthreads();
        {
          int r = tid & 127, s = tid >> 7;
          float acc = 0.f;
#pragma unroll
          for (int i = 0; i < 64; ++i) acc += wp[i] * s_x[64 * s + i];
          s_p[s * 128 + r] = acc;
        }
        __syncthreads();
        if (tid < 128) {
          int f = t >> 7;
          float hv = s_p[tid] + s_p[128 + tid] + s_p[256 + tid] + s_p[384 + tid]
                   + s_cond[f * 128 + tid] + tv;
          s_h[tid] = fmaxf(hv, 0.f);
        }
        __syncthreads();
        {
          int cc = tid & 255, s2 = tid >> 8;
          float acc = 0.f;
#pragma unroll
          for (int i = 0; i < 64; ++i) acc += wo[i] * s_h[64 * s2 + i];
          s_p[s2 * 256 + cc] = acc;
        }
        __syncthreads();
        if (tid < 256) stc(zout + tid, s_p[tid] + s_p[256 + tid]);
        __syncthreads();
        if (tid == 0) post(iflags + FZ(j, side), t + 1);
      }
    }

  } else {
    // ---------------- helpers: past taps, run ahead of the chain -----------
    const int j = bid - 22;               // 1..10
    const int dj = 1 << j, maskj = 2 * dj - 1;
    float wq[128];
    {
      const float* W = WV_past + j * 65536;
      int r = tid & 255, s2 = tid >> 8;
#pragma unroll
      for (int i = 0; i < 128; ++i) wq[i] = W[r * 256 + 128 * s2 + i];
    }
    float* ringj = ws + OFF_RINGS + 512 * (dj - 1);
    float* tapj = ws + OFF_TAPS + (j - 1) * 16 * 256;
    const int lag = (dj < 16) ? dj : 16;  // covers ring availability + tap-ring backpressure

    for (int t = 0; t < T_STEPS; ++t) {
      int want = t - lag + 1;
      if (tid == 0 && want >= 1) wait1(iflags + FZ(j, 0), want);
      __syncthreads();
      if (t >= dj) {
        if (tid < 256) s_x[tid] = ldc(ringj + ((t - dj) & maskj) * 256 + tid);
        __syncthreads();
        int r = tid & 255, s2 = tid >> 8;
        float acc = 0.f;
#pragma unroll
        for (int i = 0; i < 128; ++i) acc += wq[i] * s_x[128 * s2 + i];
        s_p[s2 * 256 + r] = acc;
        __syncthreads();
        if (tid < 256) stc(tapj + (t & 15) * 256 + tid, s_p[tid] + s_p[256 + tid]);
      } else {
        if (tid < 256) stc(tapj + (t & 15) * 256 + tid, 0.f);  // ring buffer still zero
      }
      __syncthreads();
      if (tid == 0) post(iflags + FTAP(j), t + 1);
    }
  }
}

extern "C" void kernel_launch(void* const* d_in, const int* in_sizes, int n_in,
                              void* d_out, int out_size, void* d_ws, size_t ws_size,
                              hipStream_t stream) {
  const float* y       = (const float*)d_in[0];
  const float* samples = (const float*)d_in[1];
  const float* emb_raw = (const float*)d_in[2];
  const float* condW   = (const float*)d_in[3];
  const float* WV_past = (const float*)d_in[4];
  const float* WV_pres = (const float*)d_in[5];
  const float* W_o_w   = (const float*)d_in[6];
  const float* W_o_b   = (const float*)d_in[7];
  const float* end_w   = (const float*)d_in[8];
  const float* end_b   = (const float*)d_in[9];
  (void)in_sizes; (void)n_in; (void)out_size; (void)ws_size;
  hipLaunchKernelGGL(fftnet_kernel, dim3(NBLK), dim3(512), 0, stream,
                     y, samples, emb_raw, condW, WV_past, WV_pres,
                     W_o_w, W_o_b, end_w, end_b, (int*)d_out, (float*)d_ws);
}